// Round 7
// baseline (241.700 us; speedup 1.0000x reference)
//
#include <hip/hip_runtime.h>
#include <hip/hip_cooperative_groups.h>

namespace cg = cooperative_groups;

// ---------------------------------------------------------------------------
// GCN 2-layer encoder for MI355X.
//   build (ONE cooperative kernel: hist -> scanA -> scanB -> scatter ->
//          bucketize, + wtrans folded into phase 0; emits Wt1/Wt2, CSR bucket,
//          dinv, nod[] = {start,end,dinv_bits,0})
//   -> MFMA-GEMM1(f32 in ->bf16,*dinv) -> AGG1(+b1,relu -> bf16 a1)
//   -> MFMA-GEMM2(bf16 in ->bf16,*dinv) -> AGG2(+b2 -> f32 out)
// out[r] = dinv[r] * (sum_{e: row=r} hs[col_e] + hs[r]) + b   with hs = (X@W)*dinv
// AGG gathers: 16B/lane, lane-group-strided loops (uniform, unroll x2),
// 4 nodes per 256-thread block, cross-group shfl_xor reduce.
// ---------------------------------------------------------------------------

#define CHUNKS 256             // edge chunks == build grid size

typedef short bf16x8 __attribute__((ext_vector_type(8)));
typedef float f32x4 __attribute__((ext_vector_type(4)));

__device__ __forceinline__ float bf2f(unsigned int u16) {
    return __uint_as_float(u16 << 16);
}
__device__ __forceinline__ unsigned int f2bf_rne(float f) {
    unsigned int u = __float_as_uint(f);
    return (u + 0x7fffu + ((u >> 16) & 1u)) >> 16;
}
__device__ __forceinline__ unsigned int pack2bf(float a, float b) {
    return f2bf_rne(a) | (f2bf_rne(b) << 16);
}
__device__ __forceinline__ void add8(float* acc, uint4 p) {
    acc[0] += bf2f(p.x & 0xffffu); acc[1] += bf2f(p.x >> 16);
    acc[2] += bf2f(p.y & 0xffffu); acc[3] += bf2f(p.y >> 16);
    acc[4] += bf2f(p.z & 0xffffu); acc[5] += bf2f(p.z >> 16);
    acc[6] += bf2f(p.w & 0xffffu); acc[7] += bf2f(p.w >> 16);
}

// ------------------------- cooperative build kernel ------------------------
// grid = 256 blocks x 256 threads. Phases separated by grid.sync().

__global__ __launch_bounds__(256) void build_kernel(
    const int* __restrict__ row, const int* __restrict__ col, int E, int CE, int NB,
    const float* __restrict__ W1, const float* __restrict__ W2,
    unsigned short* __restrict__ Wt1, unsigned short* __restrict__ Wt2,
    int* __restrict__ cnt, int* __restrict__ tot, int* __restrict__ bstart,
    unsigned int* __restrict__ bucket, float* __restrict__ dinv,
    int4* __restrict__ nod, int N)
{
    cg::grid_group grid = cg::this_grid();
    __shared__ unsigned int ent[8192];     // 32KB (bucketize staging)
    __shared__ int sA[256], sB[256], sC[256];
    const int b = blockIdx.x, t = threadIdx.x;

    // ---- P0: per-chunk histogram (bucket = row>>8) + wtrans ----
    sA[t] = 0;
    __syncthreads();
    {
        int s = b * CE, e = min(E, s + CE);
        for (int i = s + t; i < e; i += 256) atomicAdd(&sA[row[i] >> 8], 1);
        int i = b * 256 + t;               // wtrans: 24576 total elements
        if (i < 128 * 128) {
            int k = i >> 7, c = i & 127;
            Wt1[c * 128 + k] = (unsigned short)f2bf_rne(W1[i]);
        } else if (i < 128 * 128 + 128 * 64) {
            int j = i - 128 * 128;
            int k = j >> 6, c = j & 63;
            Wt2[c * 128 + k] = (unsigned short)f2bf_rne(W2[j]);
        }
        __syncthreads();
        if (t < NB) cnt[t * CHUNKS + b] = sA[t];
    }
    grid.sync();

    // ---- P1: per-bucket exclusive scan over chunks (blocks < NB) ----
    if (b < NB) {
        int v = cnt[b * CHUNKS + t];
        sB[t] = v; __syncthreads();
        #pragma unroll
        for (int d = 1; d < 256; d <<= 1) {
            int xv = (t >= d) ? sB[t - d] : 0;
            __syncthreads();
            sB[t] += xv;
            __syncthreads();
        }
        cnt[b * CHUNKS + t] = sB[t] - v;
        if (t == 255) tot[b] = sB[255];
    }
    grid.sync();

    // ---- P2: scan bucket totals (block 0) ----
    if (b == 0) {
        int v = (t < NB) ? tot[t] : 0;
        sC[t] = v; __syncthreads();
        #pragma unroll
        for (int d = 1; d < 256; d <<= 1) {
            int xv = (t >= d) ? sC[t - d] : 0;
            __syncthreads();
            sC[t] += xv;
            __syncthreads();
        }
        if (t < NB) bstart[t] = sC[t] - v;
        if (t == 0) bstart[NB] = E;
    }
    grid.sync();

    // ---- P3: scatter packed (rlocal | col<<8) via block-private LDS cursors ----
    {
        if (t < NB) sA[t] = bstart[t] + cnt[t * CHUNKS + b];
        __syncthreads();
        int s = b * CE, e = min(E, s + CE);
        for (int i = s + t; i < e; i += 256) {
            int r = row[i];
            int pos = atomicAdd(&sA[r >> 8], 1);
            bucket[pos] = (unsigned)(r & 255) | ((unsigned)col[i] << 8);
        }
    }
    grid.sync();

    // ---- P4: bucketize (blocks < NB): LDS hist + scan + in-place CSR ----
    if (b < NB) {
        sA[t] = 0;                          // hist
        sC[t] = 0;                          // cnt2
        __syncthreads();
        const int bs = bstart[b], be = bstart[b + 1];
        const int m = min(be - bs, 8192);
        for (int i = t; i < m; i += 256) {
            unsigned int v = bucket[bs + i];
            ent[i] = v;
            atomicAdd(&sA[v & 255u], 1);
        }
        __syncthreads();
        int h = sA[t];
        sB[t] = h;
        __syncthreads();
        #pragma unroll
        for (int d = 1; d < 256; d <<= 1) {
            int xv = (t >= d) ? sB[t - d] : 0;
            __syncthreads();
            sB[t] += xv;
            __syncthreads();
        }
        int base = sB[t] - h;
        int node = b * 256 + t;
        if (node < N) {
            float dv = rsqrtf((float)(h + 1));   // +1 self loop
            dinv[node] = dv;
            nod[node] = make_int4(bs + base, bs + base + h, __float_as_int(dv), 0);
        }
        sB[t] = base;
        __syncthreads();
        for (int i = t; i < m; i += 256) {
            unsigned int v = ent[i];
            int r = v & 255u;
            int slot = atomicAdd(&sC[r], 1);
            bucket[bs + sB[r] + slot] = v >> 8;   // col
        }
    }
}

// ------------------------------- GEMMs -------------------------------------

// out[m][c] = bf16( dinv[m] * sum_k bf16(X[m][k]) * Wt[c][k] ),  COUT = CT*64.
// Block: 64 rows x COUT cols, 4 waves. LDS row stride 256B, XOR-swizzle
// cb ^= (row&7)<<4 on both write and read. BF16IN: X already bf16 row-major.
template <int CT, bool BF16IN>
__global__ __launch_bounds__(256) void gemm_mfma_kernel(
    const void* __restrict__ Xv, const unsigned short* __restrict__ Wt,
    const float* __restrict__ dinv, unsigned short* __restrict__ out, int N)
{
    constexpr int COUT = CT * 64;
    __shared__ unsigned short As[64 * 128];      // [row][k] bf16, swizzled
    __shared__ unsigned short Bs[COUT * 128];    // [col][k] bf16, swizzled
    __shared__ float dl[64];

    const int t = threadIdx.x;
    const int m0 = blockIdx.x * 64;

    if (BF16IN) {
        const unsigned short* X = (const unsigned short*)Xv;
        #pragma unroll
        for (int i = 0; i < 4; ++i) {
            int f = i * 256 + t;          // uint4 index into 64x128 bf16 tile
            int r = f >> 4, c16 = f & 15;
            int rg = m0 + r;
            uint4 p = (rg < N) ? ((const uint4*)X)[(size_t)rg * 16 + c16]
                               : make_uint4(0u, 0u, 0u, 0u);
            int cb = c16 * 16;
            *(uint4*)((char*)As + r * 256 + (cb ^ ((r & 7) << 4))) = p;
        }
    } else {
        const float* X = (const float*)Xv;
        #pragma unroll
        for (int i = 0; i < 8; ++i) {
            int f = i * 256 + t;          // float4 index into 64x128 f32 tile
            int r = f >> 5, c4 = f & 31;
            int rg = m0 + r;
            float4 v = (rg < N) ? ((const float4*)X)[(size_t)rg * 32 + c4]
                                : make_float4(0.f, 0.f, 0.f, 0.f);
            uint2 p;
            p.x = pack2bf(v.x, v.y);
            p.y = pack2bf(v.z, v.w);
            int cb = c4 * 8;
            *(uint2*)((char*)As + r * 256 + (cb ^ ((r & 7) << 4))) = p;
        }
    }
    #pragma unroll
    for (int i = 0; i < CT * 8; ++i) {
        int f = i * 256 + t;              // uint2 index into COUT x 128 bf16
        int r = f >> 5;
        int cb = (f & 31) * 8;
        uint2 p = ((const uint2*)Wt)[f];
        *(uint2*)((char*)Bs + r * 256 + (cb ^ ((r & 7) << 4))) = p;
    }
    if (t < 64) dl[t] = (m0 + t < N) ? dinv[m0 + t] : 0.f;
    __syncthreads();

    const int w = t >> 6, l = t & 63;
    const int lr = l & 15, lk = l >> 4;

    bf16x8 af[4][4];                       // [mt][kt]
    #pragma unroll
    for (int mt = 0; mt < 4; ++mt)
        #pragma unroll
        for (int kt = 0; kt < 4; ++kt) {
            int r = mt * 16 + lr;
            int cb = kt * 64 + lk * 16;
            af[mt][kt] = *(const bf16x8*)((const char*)As + r * 256 + (cb ^ ((r & 7) << 4)));
        }
    bf16x8 bfr[CT][4];
    #pragma unroll
    for (int ct = 0; ct < CT; ++ct)
        #pragma unroll
        for (int kt = 0; kt < 4; ++kt) {
            int c = w * (CT * 16) + ct * 16 + lr;
            int cb = kt * 64 + lk * 16;
            bfr[ct][kt] = *(const bf16x8*)((const char*)Bs + c * 256 + (cb ^ ((c & 7) << 4)));
        }

    f32x4 acc[4][CT];
    #pragma unroll
    for (int mt = 0; mt < 4; ++mt)
        #pragma unroll
        for (int ct = 0; ct < CT; ++ct)
            acc[mt][ct] = f32x4{0.f, 0.f, 0.f, 0.f};

    #pragma unroll
    for (int kt = 0; kt < 4; ++kt)
        #pragma unroll
        for (int mt = 0; mt < 4; ++mt)
            #pragma unroll
            for (int ct = 0; ct < CT; ++ct)
                acc[mt][ct] = __builtin_amdgcn_mfma_f32_16x16x32_bf16(
                    af[mt][kt], bfr[ct][kt], acc[mt][ct], 0, 0, 0);

    // epilogue: C/D layout col = lane&15, row = (lane>>4)*4 + reg
    #pragma unroll
    for (int mt = 0; mt < 4; ++mt) {
        #pragma unroll
        for (int ct = 0; ct < CT; ++ct) {
            #pragma unroll
            for (int r = 0; r < 4; ++r) {
                int rowl = mt * 16 + lk * 4 + r;
                int grow = m0 + rowl;
                if (grow < N) {
                    int c = w * (CT * 16) + ct * 16 + lr;
                    float v = acc[mt][ct][r] * dl[rowl];
                    out[(size_t)grow * COUT + c] = (unsigned short)f2bf_rne(v);
                }
            }
        }
    }
}

// ------------------------------- AGGs --------------------------------------

// AGG layer 1: C=128 bf16 rows (256B). 4 nodes per 256-thread block, one wave
// per node. Lane q=l&15 owns channels 8q..8q+7 (16B); group g=l>>4 walks
// edges j = start+g, start+g+4, ... (uniform strided loop, unroll x2).
__global__ __launch_bounds__(256) void agg1_kernel(
    const unsigned short* __restrict__ hs, const unsigned int* __restrict__ csr,
    const int4* __restrict__ nod, const float* __restrict__ bias,
    unsigned short* __restrict__ out, int N)
{
    const int w = threadIdx.x >> 6, l = threadIdx.x & 63;
    const int n = blockIdx.x * 4 + w;
    if (n >= N) return;
    const int q = l & 15, g = l >> 4;

    int4 se = nod[n];
    float acc[8] = {};
    if (g == 0)                                        // self loop
        add8(acc, *(const uint4*)&hs[(size_t)n * 128 + q * 8]);

    int j = se.x + g;
    const int e = se.y;
    for (; j + 4 < e; j += 8) {
        int c0 = csr[j], c1 = csr[j + 4];
        uint4 p0 = *(const uint4*)&hs[(size_t)c0 * 128 + q * 8];
        uint4 p1 = *(const uint4*)&hs[(size_t)c1 * 128 + q * 8];
        add8(acc, p0);
        add8(acc, p1);
    }
    if (j < e)
        add8(acc, *(const uint4*)&hs[(size_t)csr[j] * 128 + q * 8]);

    #pragma unroll
    for (int i = 0; i < 8; ++i) {
        acc[i] += __shfl_xor(acc[i], 16);
        acc[i] += __shfl_xor(acc[i], 32);
    }

    if (g == 0) {
        float d = __int_as_float(se.z);
        float4 b0 = ((const float4*)bias)[q * 2];
        float4 b1 = ((const float4*)bias)[q * 2 + 1];
        float v0 = fmaxf(d * acc[0] + b0.x, 0.f), v1 = fmaxf(d * acc[1] + b0.y, 0.f);
        float v2 = fmaxf(d * acc[2] + b0.z, 0.f), v3 = fmaxf(d * acc[3] + b0.w, 0.f);
        float v4 = fmaxf(d * acc[4] + b1.x, 0.f), v5 = fmaxf(d * acc[5] + b1.y, 0.f);
        float v6 = fmaxf(d * acc[6] + b1.z, 0.f), v7 = fmaxf(d * acc[7] + b1.w, 0.f);
        uint4 o;
        o.x = pack2bf(v0, v1); o.y = pack2bf(v2, v3);
        o.z = pack2bf(v4, v5); o.w = pack2bf(v6, v7);
        *(uint4*)&out[(size_t)n * 128 + q * 8] = o;
    }
}

// AGG layer 2: C=64 bf16 rows (128B). 4 nodes per 256-thread block, one wave
// per node. Lane q=l&7 owns channels 8q..8q+7; group g=l>>3 strides by 8.
__global__ __launch_bounds__(256) void agg2_kernel(
    const unsigned short* __restrict__ hs, const unsigned int* __restrict__ csr,
    const int4* __restrict__ nod, const float* __restrict__ bias,
    float* __restrict__ out, int N)
{
    const int w = threadIdx.x >> 6, l = threadIdx.x & 63;
    const int n = blockIdx.x * 4 + w;
    if (n >= N) return;
    const int q = l & 7, g = l >> 3;

    int4 se = nod[n];
    float acc[8] = {};
    if (g == 0)                                        // self loop
        add8(acc, *(const uint4*)&hs[(size_t)n * 64 + q * 8]);

    int j = se.x + g;
    const int e = se.y;
    for (; j + 8 < e; j += 16) {
        int c0 = csr[j], c1 = csr[j + 8];
        uint4 p0 = *(const uint4*)&hs[(size_t)c0 * 64 + q * 8];
        uint4 p1 = *(const uint4*)&hs[(size_t)c1 * 64 + q * 8];
        add8(acc, p0);
        add8(acc, p1);
    }
    if (j < e)
        add8(acc, *(const uint4*)&hs[(size_t)csr[j] * 64 + q * 8]);

    #pragma unroll
    for (int i = 0; i < 8; ++i) {
        acc[i] += __shfl_xor(acc[i], 8);
        acc[i] += __shfl_xor(acc[i], 16);
        acc[i] += __shfl_xor(acc[i], 32);
    }

    if (g == 0) {
        float d = __int_as_float(se.z);
        float4 b0 = ((const float4*)bias)[q * 2];
        float4 b1 = ((const float4*)bias)[q * 2 + 1];
        float4 o0, o1;
        o0.x = d * acc[0] + b0.x; o0.y = d * acc[1] + b0.y;
        o0.z = d * acc[2] + b0.z; o0.w = d * acc[3] + b0.w;
        o1.x = d * acc[4] + b1.x; o1.y = d * acc[5] + b1.y;
        o1.z = d * acc[6] + b1.z; o1.w = d * acc[7] + b1.w;
        *(float4*)&out[(size_t)n * 64 + q * 8] = o0;
        *(float4*)&out[(size_t)n * 64 + q * 8 + 4] = o1;
    }
}

extern "C" void kernel_launch(void* const* d_in, const int* in_sizes, int n_in,
                              void* d_out, int out_size, void* d_ws, size_t ws_size,
                              hipStream_t stream)
{
    const float* x  = (const float*)d_in[0];
    const int*   ei = (const int*)d_in[1];
    const float* W1 = (const float*)d_in[2];
    const float* b1 = (const float*)d_in[3];
    const float* W2 = (const float*)d_in[4];
    const float* b2 = (const float*)d_in[5];
    float* out = (float*)d_out;

    const int N = in_sizes[0] / 128;          // 50000
    const int E = in_sizes[1] / 2;            // 800000
    const int* row = ei;                       // targets
    const int* col = ei + E;                   // sources
    const int NB = (N + 255) / 256;            // 196 buckets
    const int CE = (E + CHUNKS - 1) / CHUNKS;  // 3125 edges per chunk

    // workspace layout (256B aligned)
    char* ws = (char*)d_ws;
    size_t o = 0;
    auto take = [&](size_t bytes) { void* p = ws + o; o = (o + bytes + 255) & ~(size_t)255; return p; };
    int*   cnt    = (int*)  take((size_t)NB * CHUNKS * 4);
    int*   tot    = (int*)  take((size_t)NB * 4);
    int*   bstart = (int*)  take((size_t)(NB + 1) * 4);
    unsigned int* bucket = (unsigned int*)take((size_t)E * 4);   // packed -> in-place CSR
    float* dinv   = (float*)take((size_t)N * 4);
    int4*  nod    = (int4*) take((size_t)N * 16);
    unsigned short* Wt1 = (unsigned short*)take(128 * 128 * 2);
    unsigned short* Wt2 = (unsigned short*)take(64 * 128 * 2);
    unsigned short* hs  = (unsigned short*)take((size_t)N * 128 * 2);  // bf16, reused as hs2
    unsigned short* a1  = (unsigned short*)take((size_t)N * 128 * 2);  // layer-1 acts bf16
    unsigned short* hs2 = hs;                                           // alias

    {
        int E_ = E, CE_ = CE, NB_ = NB, N_ = N;
        void* args[] = {
            (void*)&row, (void*)&col, (void*)&E_, (void*)&CE_, (void*)&NB_,
            (void*)&W1, (void*)&W2, (void*)&Wt1, (void*)&Wt2,
            (void*)&cnt, (void*)&tot, (void*)&bstart,
            (void*)&bucket, (void*)&dinv, (void*)&nod, (void*)&N_
        };
        hipLaunchCooperativeKernel((void*)build_kernel, dim3(CHUNKS), dim3(256),
                                   args, 0, stream);
    }

    // layer 1
    gemm_mfma_kernel<2, false><<<(N + 63) / 64, 256, 0, stream>>>(x, Wt1, dinv, hs, N);
    agg1_kernel<<<(N + 3) / 4, 256, 0, stream>>>(hs, bucket, nod, b1, a1, N);

    // layer 2
    gemm_mfma_kernel<1, true><<<(N + 63) / 64, 256, 0, stream>>>(a1, Wt2, dinv, hs2, N);
    agg2_kernel<<<(N + 3) / 4, 256, 0, stream>>>(hs2, bucket, nod, b2, out, N);
}

// Round 8
// 109.094 us; speedup vs baseline: 2.2155x; 2.2155x over previous
//
#include <hip/hip_runtime.h>

// ---------------------------------------------------------------------------
// GCN 2-layer encoder for MI355X.
//   p1 (per-chunk LDS hist+scan+private-region scatter, + wtrans folded in)
//   p2 (per-bucket fragment gather -> LDS hist+scan -> fixed-base CSR, nod/dinv)
//   -> MFMA-GEMM1(f32 in ->bf16,*dinv) -> AGG1(+b1,relu -> bf16 a1)
//   -> MFMA-GEMM2(bf16 in ->bf16,*dinv) -> AGG2(+b2 -> f32 out)
// out[r] = dinv[r] * (sum_{e: row=r} hs[col_e] + hs[r]) + b   with hs = (X@W)*dinv
// NO global coordination in the build: chunk regions are block-private; final
// CSR uses fixed per-bucket base b*CAP (CAP=7168 >> mean 4096 + 5 sigma).
// Lesson r7: grid.sync() costs ~35us/sync on 8 non-coherent XCDs -- never.
// ---------------------------------------------------------------------------

#define CHUNKS 256             // edge chunks (p1 grid)
#define CAP    7168            // per-bucket CSR capacity (and LDS ent capacity)

typedef short bf16x8 __attribute__((ext_vector_type(8)));
typedef float f32x4 __attribute__((ext_vector_type(4)));

__device__ __forceinline__ float bf2f(unsigned int u16) {
    return __uint_as_float(u16 << 16);
}
__device__ __forceinline__ unsigned int f2bf_rne(float f) {
    unsigned int u = __float_as_uint(f);
    return (u + 0x7fffu + ((u >> 16) & 1u)) >> 16;
}
__device__ __forceinline__ unsigned int pack2bf(float a, float b) {
    return f2bf_rne(a) | (f2bf_rne(b) << 16);
}
__device__ __forceinline__ void add8(float* acc, uint4 p) {
    acc[0] += bf2f(p.x & 0xffffu); acc[1] += bf2f(p.x >> 16);
    acc[2] += bf2f(p.y & 0xffffu); acc[3] += bf2f(p.y >> 16);
    acc[4] += bf2f(p.z & 0xffffu); acc[5] += bf2f(p.z >> 16);
    acc[6] += bf2f(p.w & 0xffffu); acc[7] += bf2f(p.w >> 16);
}

// ------------------------------ build p1 -----------------------------------
// Chunk c: LDS hist by bucket (row>>8), LDS scan, scatter packed entries
// (rlocal | col<<8) grouped-by-bucket into private region [c*CE, ...).
// Emits pos[b][c] = within-chunk exclusive offset of bucket b (rows 0..NB).
// Also converts W1/W2 -> bf16 col-major (wtrans folded in).
__global__ __launch_bounds__(256) void p1_kernel(
    const int* __restrict__ row, const int* __restrict__ col, int E, int CE, int NB,
    const float* __restrict__ W1, const float* __restrict__ W2,
    unsigned short* __restrict__ Wt1, unsigned short* __restrict__ Wt2,
    int* __restrict__ pos, unsigned int* __restrict__ bucketc)
{
    __shared__ int hist[256], scn[256], cur[256];
    const int c = blockIdx.x, t = threadIdx.x;
    const int s = c * CE, e = min(E, s + CE);

    hist[t] = 0;
    __syncthreads();
    for (int i = s + t; i < e; i += 256) atomicAdd(&hist[row[i] >> 8], 1);
    {   // wtrans: 24576 elements over the grid
        int i = c * 256 + t;
        if (i < 128 * 128) {
            int k = i >> 7, cc = i & 127;
            Wt1[cc * 128 + k] = (unsigned short)f2bf_rne(W1[i]);
        } else if (i < 128 * 128 + 128 * 64) {
            int j = i - 128 * 128;
            int k = j >> 6, cc = j & 63;
            Wt2[cc * 128 + k] = (unsigned short)f2bf_rne(W2[j]);
        }
    }
    __syncthreads();

    int v = hist[t];
    scn[t] = v;
    __syncthreads();
    #pragma unroll
    for (int d = 1; d < 256; d <<= 1) {
        int xv = (t >= d) ? scn[t - d] : 0;
        __syncthreads();
        scn[t] += xv;
        __syncthreads();
    }
    int excl = scn[t] - v;
    if (t <= NB) pos[t * CHUNKS + c] = excl;   // row NB = chunk total
    cur[t] = excl;
    __syncthreads();

    for (int i = s + t; i < e; i += 256) {
        int r = row[i];
        int p = atomicAdd(&cur[r >> 8], 1);
        bucketc[s + p] = (unsigned)(r & 255) | ((unsigned)col[i] << 8);
    }
}

// ------------------------------ build p2 -----------------------------------
// Bucket b: gather fragments (one chunk per thread, unroll x2) into LDS,
// hist by rlocal, scan, emit dinv/nod, write final CSR at fixed base b*CAP.
__global__ __launch_bounds__(256) void p2_kernel(
    const int* __restrict__ pos, const unsigned int* __restrict__ bucketc,
    unsigned int* __restrict__ csrf, float* __restrict__ dinv,
    int4* __restrict__ nod, int N, int CE)
{
    __shared__ unsigned int ent[CAP];      // 28KB
    __shared__ int stmp[256], hist[256], scn[256], cnt2[256], smtot[1];
    const int b = blockIdx.x, t = threadIdx.x;

    const int p0 = pos[b * CHUNKS + t];
    const int p1 = pos[(b + 1) * CHUNKS + t];
    const int cnt = p1 - p0;

    stmp[t] = cnt;
    hist[t] = 0;
    cnt2[t] = 0;
    __syncthreads();
    #pragma unroll
    for (int d = 1; d < 256; d <<= 1) {
        int xv = (t >= d) ? stmp[t - d] : 0;
        __syncthreads();
        stmp[t] += xv;
        __syncthreads();
    }
    const int fbase = stmp[t] - cnt;
    if (t == 255) smtot[0] = stmp[255];
    __syncthreads();
    const int m = min(smtot[0], CAP);

    // gather my chunk's fragment (independent loads, unrolled x2)
    {
        const int src = t * CE + p0;
        int i = 0;
        for (; i + 1 < cnt; i += 2) {
            unsigned int u0 = bucketc[src + i];
            unsigned int u1 = bucketc[src + i + 1];
            int d0 = fbase + i;
            if (d0 + 1 < CAP) {
                ent[d0] = u0; ent[d0 + 1] = u1;
                atomicAdd(&hist[u0 & 255u], 1);
                atomicAdd(&hist[u1 & 255u], 1);
            }
        }
        if (i < cnt) {
            unsigned int u0 = bucketc[src + i];
            int d0 = fbase + i;
            if (d0 < CAP) {
                ent[d0] = u0;
                atomicAdd(&hist[u0 & 255u], 1);
            }
        }
    }
    __syncthreads();

    int h = hist[t];
    scn[t] = h;
    __syncthreads();
    #pragma unroll
    for (int d = 1; d < 256; d <<= 1) {
        int xv = (t >= d) ? scn[t - d] : 0;
        __syncthreads();
        scn[t] += xv;
        __syncthreads();
    }
    int base = scn[t] - h;

    int node = b * 256 + t;
    if (node < N) {
        float dv = rsqrtf((float)(h + 1));   // +1 self loop
        dinv[node] = dv;
        nod[node] = make_int4(b * CAP + base, b * CAP + base + h, __float_as_int(dv), 0);
    }
    scn[t] = base;
    __syncthreads();

    for (int i = t; i < m; i += 256) {
        unsigned int v = ent[i];
        int r = v & 255u;
        int slot = atomicAdd(&cnt2[r], 1);
        csrf[b * CAP + scn[r] + slot] = v >> 8;   // col
    }
}

// ------------------------------- GEMMs -------------------------------------

// out[m][c] = bf16( dinv[m] * sum_k bf16(X[m][k]) * Wt[c][k] ),  COUT = CT*64.
// Block: 64 rows x COUT cols, 4 waves. LDS row stride 256B, XOR-swizzle
// cb ^= (row&7)<<4 on both write and read. BF16IN: X already bf16 row-major.
template <int CT, bool BF16IN>
__global__ __launch_bounds__(256) void gemm_mfma_kernel(
    const void* __restrict__ Xv, const unsigned short* __restrict__ Wt,
    const float* __restrict__ dinv, unsigned short* __restrict__ out, int N)
{
    constexpr int COUT = CT * 64;
    __shared__ unsigned short As[64 * 128];      // [row][k] bf16, swizzled
    __shared__ unsigned short Bs[COUT * 128];    // [col][k] bf16, swizzled
    __shared__ float dl[64];

    const int t = threadIdx.x;
    const int m0 = blockIdx.x * 64;

    if (BF16IN) {
        const unsigned short* X = (const unsigned short*)Xv;
        #pragma unroll
        for (int i = 0; i < 4; ++i) {
            int f = i * 256 + t;          // uint4 index into 64x128 bf16 tile
            int r = f >> 4, c16 = f & 15;
            int rg = m0 + r;
            uint4 p = (rg < N) ? ((const uint4*)X)[(size_t)rg * 16 + c16]
                               : make_uint4(0u, 0u, 0u, 0u);
            int cb = c16 * 16;
            *(uint4*)((char*)As + r * 256 + (cb ^ ((r & 7) << 4))) = p;
        }
    } else {
        const float* X = (const float*)Xv;
        #pragma unroll
        for (int i = 0; i < 8; ++i) {
            int f = i * 256 + t;          // float4 index into 64x128 f32 tile
            int r = f >> 5, c4 = f & 31;
            int rg = m0 + r;
            float4 v = (rg < N) ? ((const float4*)X)[(size_t)rg * 32 + c4]
                                : make_float4(0.f, 0.f, 0.f, 0.f);
            uint2 p;
            p.x = pack2bf(v.x, v.y);
            p.y = pack2bf(v.z, v.w);
            int cb = c4 * 8;
            *(uint2*)((char*)As + r * 256 + (cb ^ ((r & 7) << 4))) = p;
        }
    }
    #pragma unroll
    for (int i = 0; i < CT * 8; ++i) {
        int f = i * 256 + t;              // uint2 index into COUT x 128 bf16
        int r = f >> 5;
        int cb = (f & 31) * 8;
        uint2 p = ((const uint2*)Wt)[f];
        *(uint2*)((char*)Bs + r * 256 + (cb ^ ((r & 7) << 4))) = p;
    }
    if (t < 64) dl[t] = (m0 + t < N) ? dinv[m0 + t] : 0.f;
    __syncthreads();

    const int w = t >> 6, l = t & 63;
    const int lr = l & 15, lk = l >> 4;

    bf16x8 af[4][4];                       // [mt][kt]
    #pragma unroll
    for (int mt = 0; mt < 4; ++mt)
        #pragma unroll
        for (int kt = 0; kt < 4; ++kt) {
            int r = mt * 16 + lr;
            int cb = kt * 64 + lk * 16;
            af[mt][kt] = *(const bf16x8*)((const char*)As + r * 256 + (cb ^ ((r & 7) << 4)));
        }
    bf16x8 bfr[CT][4];
    #pragma unroll
    for (int ct = 0; ct < CT; ++ct)
        #pragma unroll
        for (int kt = 0; kt < 4; ++kt) {
            int c = w * (CT * 16) + ct * 16 + lr;
            int cb = kt * 64 + lk * 16;
            bfr[ct][kt] = *(const bf16x8*)((const char*)Bs + c * 256 + (cb ^ ((c & 7) << 4)));
        }

    f32x4 acc[4][CT];
    #pragma unroll
    for (int mt = 0; mt < 4; ++mt)
        #pragma unroll
        for (int ct = 0; ct < CT; ++ct)
            acc[mt][ct] = f32x4{0.f, 0.f, 0.f, 0.f};

    #pragma unroll
    for (int kt = 0; kt < 4; ++kt)
        #pragma unroll
        for (int mt = 0; mt < 4; ++mt)
            #pragma unroll
            for (int ct = 0; ct < CT; ++ct)
                acc[mt][ct] = __builtin_amdgcn_mfma_f32_16x16x32_bf16(
                    af[mt][kt], bfr[ct][kt], acc[mt][ct], 0, 0, 0);

    // epilogue: C/D layout col = lane&15, row = (lane>>4)*4 + reg
    #pragma unroll
    for (int mt = 0; mt < 4; ++mt) {
        #pragma unroll
        for (int ct = 0; ct < CT; ++ct) {
            #pragma unroll
            for (int r = 0; r < 4; ++r) {
                int rowl = mt * 16 + lk * 4 + r;
                int grow = m0 + rowl;
                if (grow < N) {
                    int c = w * (CT * 16) + ct * 16 + lr;
                    float v = acc[mt][ct][r] * dl[rowl];
                    out[(size_t)grow * COUT + c] = (unsigned short)f2bf_rne(v);
                }
            }
        }
    }
}

// ------------------------------- AGGs --------------------------------------

// AGG layer 1: C=128 bf16 rows (256B). 4 nodes per 256-thread block, one wave
// per node. Lane q=l&15 owns channels 8q..8q+7 (16B); group g=l>>4 walks
// edges j = start+g, start+g+4, ... (uniform strided loop, unroll x2).
__global__ __launch_bounds__(256) void agg1_kernel(
    const unsigned short* __restrict__ hs, const unsigned int* __restrict__ csr,
    const int4* __restrict__ nod, const float* __restrict__ bias,
    unsigned short* __restrict__ out, int N)
{
    const int w = threadIdx.x >> 6, l = threadIdx.x & 63;
    const int n = blockIdx.x * 4 + w;
    if (n >= N) return;
    const int q = l & 15, g = l >> 4;

    int4 se = nod[n];
    float acc[8] = {};
    if (g == 0)                                        // self loop
        add8(acc, *(const uint4*)&hs[(size_t)n * 128 + q * 8]);

    int j = se.x + g;
    const int e = se.y;
    for (; j + 4 < e; j += 8) {
        int c0 = csr[j], c1 = csr[j + 4];
        uint4 p0 = *(const uint4*)&hs[(size_t)c0 * 128 + q * 8];
        uint4 p1 = *(const uint4*)&hs[(size_t)c1 * 128 + q * 8];
        add8(acc, p0);
        add8(acc, p1);
    }
    if (j < e)
        add8(acc, *(const uint4*)&hs[(size_t)csr[j] * 128 + q * 8]);

    #pragma unroll
    for (int i = 0; i < 8; ++i) {
        acc[i] += __shfl_xor(acc[i], 16);
        acc[i] += __shfl_xor(acc[i], 32);
    }

    if (g == 0) {
        float d = __int_as_float(se.z);
        float4 b0 = ((const float4*)bias)[q * 2];
        float4 b1 = ((const float4*)bias)[q * 2 + 1];
        float v0 = fmaxf(d * acc[0] + b0.x, 0.f), v1 = fmaxf(d * acc[1] + b0.y, 0.f);
        float v2 = fmaxf(d * acc[2] + b0.z, 0.f), v3 = fmaxf(d * acc[3] + b0.w, 0.f);
        float v4 = fmaxf(d * acc[4] + b1.x, 0.f), v5 = fmaxf(d * acc[5] + b1.y, 0.f);
        float v6 = fmaxf(d * acc[6] + b1.z, 0.f), v7 = fmaxf(d * acc[7] + b1.w, 0.f);
        uint4 o;
        o.x = pack2bf(v0, v1); o.y = pack2bf(v2, v3);
        o.z = pack2bf(v4, v5); o.w = pack2bf(v6, v7);
        *(uint4*)&out[(size_t)n * 128 + q * 8] = o;
    }
}

// AGG layer 2: C=64 bf16 rows (128B). 4 nodes per 256-thread block, one wave
// per node. Lane q=l&7 owns channels 8q..8q+7; group g=l>>3 strides by 8.
__global__ __launch_bounds__(256) void agg2_kernel(
    const unsigned short* __restrict__ hs, const unsigned int* __restrict__ csr,
    const int4* __restrict__ nod, const float* __restrict__ bias,
    float* __restrict__ out, int N)
{
    const int w = threadIdx.x >> 6, l = threadIdx.x & 63;
    const int n = blockIdx.x * 4 + w;
    if (n >= N) return;
    const int q = l & 7, g = l >> 3;

    int4 se = nod[n];
    float acc[8] = {};
    if (g == 0)                                        // self loop
        add8(acc, *(const uint4*)&hs[(size_t)n * 64 + q * 8]);

    int j = se.x + g;
    const int e = se.y;
    for (; j + 8 < e; j += 16) {
        int c0 = csr[j], c1 = csr[j + 8];
        uint4 p0 = *(const uint4*)&hs[(size_t)c0 * 64 + q * 8];
        uint4 p1 = *(const uint4*)&hs[(size_t)c1 * 64 + q * 8];
        add8(acc, p0);
        add8(acc, p1);
    }
    if (j < e)
        add8(acc, *(const uint4*)&hs[(size_t)csr[j] * 64 + q * 8]);

    #pragma unroll
    for (int i = 0; i < 8; ++i) {
        acc[i] += __shfl_xor(acc[i], 8);
        acc[i] += __shfl_xor(acc[i], 16);
        acc[i] += __shfl_xor(acc[i], 32);
    }

    if (g == 0) {
        float d = __int_as_float(se.z);
        float4 b0 = ((const float4*)bias)[q * 2];
        float4 b1 = ((const float4*)bias)[q * 2 + 1];
        float4 o0, o1;
        o0.x = d * acc[0] + b0.x; o0.y = d * acc[1] + b0.y;
        o0.z = d * acc[2] + b0.z; o0.w = d * acc[3] + b0.w;
        o1.x = d * acc[4] + b1.x; o1.y = d * acc[5] + b1.y;
        o1.z = d * acc[6] + b1.z; o1.w = d * acc[7] + b1.w;
        *(float4*)&out[(size_t)n * 64 + q * 8] = o0;
        *(float4*)&out[(size_t)n * 64 + q * 8 + 4] = o1;
    }
}

extern "C" void kernel_launch(void* const* d_in, const int* in_sizes, int n_in,
                              void* d_out, int out_size, void* d_ws, size_t ws_size,
                              hipStream_t stream)
{
    const float* x  = (const float*)d_in[0];
    const int*   ei = (const int*)d_in[1];
    const float* W1 = (const float*)d_in[2];
    const float* b1 = (const float*)d_in[3];
    const float* W2 = (const float*)d_in[4];
    const float* b2 = (const float*)d_in[5];
    float* out = (float*)d_out;

    const int N = in_sizes[0] / 128;          // 50000
    const int E = in_sizes[1] / 2;            // 800000
    const int* row = ei;                       // targets
    const int* col = ei + E;                   // sources
    const int NB = (N + 255) / 256;            // 196 buckets
    const int CE = (E + CHUNKS - 1) / CHUNKS;  // 3125 edges per chunk

    // workspace layout (256B aligned)
    char* ws = (char*)d_ws;
    size_t o = 0;
    auto take = [&](size_t bytes) { void* p = ws + o; o = (o + bytes + 255) & ~(size_t)255; return p; };
    int*   pos    = (int*)  take((size_t)(NB + 1) * CHUNKS * 4);
    unsigned int* bucketc = (unsigned int*)take((size_t)E * 4);       // chunk-private regions
    unsigned int* csrf    = (unsigned int*)take((size_t)NB * CAP * 4); // final CSR, base b*CAP
    float* dinv   = (float*)take((size_t)N * 4);
    int4*  nod    = (int4*) take((size_t)N * 16);
    unsigned short* Wt1 = (unsigned short*)take(128 * 128 * 2);
    unsigned short* Wt2 = (unsigned short*)take(64 * 128 * 2);
    unsigned short* hs  = (unsigned short*)take((size_t)N * 128 * 2);  // bf16, reused as hs2
    unsigned short* a1  = (unsigned short*)take((size_t)N * 128 * 2);  // layer-1 acts bf16
    unsigned short* hs2 = hs;                                           // alias

    p1_kernel<<<CHUNKS, 256, 0, stream>>>(row, col, E, CE, NB, W1, W2, Wt1, Wt2,
                                          pos, bucketc);
    p2_kernel<<<NB, 256, 0, stream>>>(pos, bucketc, csrf, dinv, nod, N, CE);

    // layer 1
    gemm_mfma_kernel<2, false><<<(N + 63) / 64, 256, 0, stream>>>(x, Wt1, dinv, hs, N);
    agg1_kernel<<<(N + 3) / 4, 256, 0, stream>>>(hs, csrf, nod, b1, a1, N);

    // layer 2
    gemm_mfma_kernel<1, true><<<(N + 63) / 64, 256, 0, stream>>>(a1, Wt2, dinv, hs2, N);
    agg2_kernel<<<(N + 3) / 4, 256, 0, stream>>>(hs2, csrf, nod, b2, out, N);
}

// Round 10
// 102.971 us; speedup vs baseline: 2.3473x; 1.0595x over previous
//
#include <hip/hip_runtime.h>

// ---------------------------------------------------------------------------
// GCN 2-layer encoder for MI355X.
//   p1 (per-chunk LDS hist+scan+private-region scatter, + wtrans folded in)
//   p2 (per-bucket fragment gather -> LDS hist+scan -> fixed-base CSR, nod/dinv)
//   -> MFMA-GEMM1(f32 in ->bf16,*dinv) -> FUSED AGG1+GEMM2 (aggregate 64
//      nodes/block into LDS a1 tile, MFMA vs Wt2, write hs2) -> AGG2(+b2)
// out[r] = dinv[r] * (sum_{e: row=r} hs[col_e] + hs[r]) + b   with hs = (X@W)*dinv
// Lesson r7: grid.sync() costs ~35us/sync on 8 non-coherent XCDs -- never.
// Lesson r9: wave->row map must cover the WHOLE LDS tile (n0+w covered only
//   16/64 rows -> uninit LDS -> NaN). Now each wave owns 4 nodes: lane l ->
//   (sub=l>>4, q=l&15), node = n0 + w*4 + sub, lane q owns channels 8q..8q+7
//   exclusively (no reduce needed; every As granule written).
// ---------------------------------------------------------------------------

#define CHUNKS 256             // edge chunks (p1 grid)
#define CAP    7168            // per-bucket CSR capacity (and LDS ent capacity)

typedef short bf16x8 __attribute__((ext_vector_type(8)));
typedef float f32x4 __attribute__((ext_vector_type(4)));

__device__ __forceinline__ float bf2f(unsigned int u16) {
    return __uint_as_float(u16 << 16);
}
__device__ __forceinline__ unsigned int f2bf_rne(float f) {
    unsigned int u = __float_as_uint(f);
    return (u + 0x7fffu + ((u >> 16) & 1u)) >> 16;
}
__device__ __forceinline__ unsigned int pack2bf(float a, float b) {
    return f2bf_rne(a) | (f2bf_rne(b) << 16);
}
__device__ __forceinline__ void add8(float* acc, uint4 p) {
    acc[0] += bf2f(p.x & 0xffffu); acc[1] += bf2f(p.x >> 16);
    acc[2] += bf2f(p.y & 0xffffu); acc[3] += bf2f(p.y >> 16);
    acc[4] += bf2f(p.z & 0xffffu); acc[5] += bf2f(p.z >> 16);
    acc[6] += bf2f(p.w & 0xffffu); acc[7] += bf2f(p.w >> 16);
}

// ------------------------------ build p1 -----------------------------------
__global__ __launch_bounds__(256) void p1_kernel(
    const int* __restrict__ row, const int* __restrict__ col, int E, int CE, int NB,
    const float* __restrict__ W1, const float* __restrict__ W2,
    unsigned short* __restrict__ Wt1, unsigned short* __restrict__ Wt2,
    int* __restrict__ pos, unsigned int* __restrict__ bucketc)
{
    __shared__ int hist[256], scn[256], cur[256];
    const int c = blockIdx.x, t = threadIdx.x;
    const int s = c * CE, e = min(E, s + CE);

    hist[t] = 0;
    __syncthreads();
    for (int i = s + t; i < e; i += 256) atomicAdd(&hist[row[i] >> 8], 1);
    {   // wtrans: 24576 elements over the grid
        int i = c * 256 + t;
        if (i < 128 * 128) {
            int k = i >> 7, cc = i & 127;
            Wt1[cc * 128 + k] = (unsigned short)f2bf_rne(W1[i]);
        } else if (i < 128 * 128 + 128 * 64) {
            int j = i - 128 * 128;
            int k = j >> 6, cc = j & 63;
            Wt2[cc * 128 + k] = (unsigned short)f2bf_rne(W2[j]);
        }
    }
    __syncthreads();

    int v = hist[t];
    scn[t] = v;
    __syncthreads();
    #pragma unroll
    for (int d = 1; d < 256; d <<= 1) {
        int xv = (t >= d) ? scn[t - d] : 0;
        __syncthreads();
        scn[t] += xv;
        __syncthreads();
    }
    int excl = scn[t] - v;
    if (t <= NB) pos[t * CHUNKS + c] = excl;   // row NB = chunk total
    cur[t] = excl;
    __syncthreads();

    for (int i = s + t; i < e; i += 256) {
        int r = row[i];
        int p = atomicAdd(&cur[r >> 8], 1);
        bucketc[s + p] = (unsigned)(r & 255) | ((unsigned)col[i] << 8);
    }
}

// ------------------------------ build p2 -----------------------------------
__global__ __launch_bounds__(256) void p2_kernel(
    const int* __restrict__ pos, const unsigned int* __restrict__ bucketc,
    unsigned int* __restrict__ csrf, float* __restrict__ dinv,
    int4* __restrict__ nod, int N, int CE)
{
    __shared__ unsigned int ent[CAP];      // 28KB
    __shared__ int stmp[256], hist[256], scn[256], cnt2[256], smtot[1];
    const int b = blockIdx.x, t = threadIdx.x;

    const int p0 = pos[b * CHUNKS + t];
    const int p1 = pos[(b + 1) * CHUNKS + t];
    const int cnt = p1 - p0;

    stmp[t] = cnt;
    hist[t] = 0;
    cnt2[t] = 0;
    __syncthreads();
    #pragma unroll
    for (int d = 1; d < 256; d <<= 1) {
        int xv = (t >= d) ? stmp[t - d] : 0;
        __syncthreads();
        stmp[t] += xv;
        __syncthreads();
    }
    const int fbase = stmp[t] - cnt;
    if (t == 255) smtot[0] = stmp[255];
    __syncthreads();
    const int m = min(smtot[0], CAP);

    {
        const int src = t * CE + p0;
        int i = 0;
        for (; i + 1 < cnt; i += 2) {
            unsigned int u0 = bucketc[src + i];
            unsigned int u1 = bucketc[src + i + 1];
            int d0 = fbase + i;
            if (d0 + 1 < CAP) {
                ent[d0] = u0; ent[d0 + 1] = u1;
                atomicAdd(&hist[u0 & 255u], 1);
                atomicAdd(&hist[u1 & 255u], 1);
            }
        }
        if (i < cnt) {
            unsigned int u0 = bucketc[src + i];
            int d0 = fbase + i;
            if (d0 < CAP) {
                ent[d0] = u0;
                atomicAdd(&hist[u0 & 255u], 1);
            }
        }
    }
    __syncthreads();

    int h = hist[t];
    scn[t] = h;
    __syncthreads();
    #pragma unroll
    for (int d = 1; d < 256; d <<= 1) {
        int xv = (t >= d) ? scn[t - d] : 0;
        __syncthreads();
        scn[t] += xv;
        __syncthreads();
    }
    int base = scn[t] - h;

    int node = b * 256 + t;
    if (node < N) {
        float dv = rsqrtf((float)(h + 1));   // +1 self loop
        dinv[node] = dv;
        nod[node] = make_int4(b * CAP + base, b * CAP + base + h, __float_as_int(dv), 0);
    }
    scn[t] = base;
    __syncthreads();

    for (int i = t; i < m; i += 256) {
        unsigned int v = ent[i];
        int r = v & 255u;
        int slot = atomicAdd(&cnt2[r], 1);
        csrf[b * CAP + scn[r] + slot] = v >> 8;   // col
    }
}

// ------------------------------- GEMM1 -------------------------------------
// out[m][c] = bf16( dinv[m] * sum_k bf16(X[m][k]) * Wt[c][k] ), COUT=128.
__global__ __launch_bounds__(256) void gemm_mfma_kernel(
    const float* __restrict__ X, const unsigned short* __restrict__ Wt,
    const float* __restrict__ dinv, unsigned short* __restrict__ out, int N)
{
    constexpr int COUT = 128;
    __shared__ unsigned short As[64 * 128];      // [row][k] bf16, swizzled
    __shared__ unsigned short Bs[COUT * 128];    // [col][k] bf16, swizzled
    __shared__ float dl[64];

    const int t = threadIdx.x;
    const int m0 = blockIdx.x * 64;

    #pragma unroll
    for (int i = 0; i < 8; ++i) {
        int f = i * 256 + t;          // float4 index into 64x128 f32 tile
        int r = f >> 5, c4 = f & 31;
        int rg = m0 + r;
        float4 v = (rg < N) ? ((const float4*)X)[(size_t)rg * 32 + c4]
                            : make_float4(0.f, 0.f, 0.f, 0.f);
        uint2 p;
        p.x = pack2bf(v.x, v.y);
        p.y = pack2bf(v.z, v.w);
        int cb = c4 * 8;
        *(uint2*)((char*)As + r * 256 + (cb ^ ((r & 7) << 4))) = p;
    }
    #pragma unroll
    for (int i = 0; i < 16; ++i) {
        int f = i * 256 + t;              // uint2 index into COUT x 128 bf16
        int r = f >> 5;
        int cb = (f & 31) * 8;
        uint2 p = ((const uint2*)Wt)[f];
        *(uint2*)((char*)Bs + r * 256 + (cb ^ ((r & 7) << 4))) = p;
    }
    if (t < 64) dl[t] = (m0 + t < N) ? dinv[m0 + t] : 0.f;
    __syncthreads();

    const int w = t >> 6, l = t & 63;
    const int lr = l & 15, lk = l >> 4;

    bf16x8 af[4][4];                       // [mt][kt]
    #pragma unroll
    for (int mt = 0; mt < 4; ++mt)
        #pragma unroll
        for (int kt = 0; kt < 4; ++kt) {
            int r = mt * 16 + lr;
            int cb = kt * 64 + lk * 16;
            af[mt][kt] = *(const bf16x8*)((const char*)As + r * 256 + (cb ^ ((r & 7) << 4)));
        }
    bf16x8 bfr[2][4];
    #pragma unroll
    for (int ct = 0; ct < 2; ++ct)
        #pragma unroll
        for (int kt = 0; kt < 4; ++kt) {
            int c = w * 32 + ct * 16 + lr;
            int cb = kt * 64 + lk * 16;
            bfr[ct][kt] = *(const bf16x8*)((const char*)Bs + c * 256 + (cb ^ ((c & 7) << 4)));
        }

    f32x4 acc[4][2];
    #pragma unroll
    for (int mt = 0; mt < 4; ++mt)
        #pragma unroll
        for (int ct = 0; ct < 2; ++ct)
            acc[mt][ct] = f32x4{0.f, 0.f, 0.f, 0.f};

    #pragma unroll
    for (int kt = 0; kt < 4; ++kt)
        #pragma unroll
        for (int mt = 0; mt < 4; ++mt)
            #pragma unroll
            for (int ct = 0; ct < 2; ++ct)
                acc[mt][ct] = __builtin_amdgcn_mfma_f32_16x16x32_bf16(
                    af[mt][kt], bfr[ct][kt], acc[mt][ct], 0, 0, 0);

    // epilogue: C/D layout col = lane&15, row = (lane>>4)*4 + reg
    #pragma unroll
    for (int mt = 0; mt < 4; ++mt) {
        #pragma unroll
        for (int ct = 0; ct < 2; ++ct) {
            #pragma unroll
            for (int r = 0; r < 4; ++r) {
                int rowl = mt * 16 + lk * 4 + r;
                int grow = m0 + rowl;
                if (grow < N) {
                    int c = w * 32 + ct * 16 + lr;
                    float v = acc[mt][ct][r] * dl[rowl];
                    out[(size_t)grow * COUT + c] = (unsigned short)f2bf_rne(v);
                }
            }
        }
    }
}

// --------------------- FUSED AGG1 + GEMM2 ----------------------------------
// Block = 64 nodes, 16 waves (1024 thr). Wave w owns 4 nodes: lane l ->
// (sub = l>>4, q = l&15); node n = n0 + w*4 + sub; lane q owns channels
// 8q..8q+7 EXCLUSIVELY (16B uint4 loads, no cross-lane reduce). Each 16-lane
// group walks its node's edge list (unroll x2 -> 8 rows in flight per wave).
// a1 row = relu(dv*acc + b1) -> LDS As (swizzled). One barrier, then
// 64x64x128 MFMA vs LDS Bs=Wt2 (wave w -> tile mt=w>>2, ct=w&3), epilogue
// scales by dinv (dl) and writes hs2 bf16.
__global__ __launch_bounds__(1024) void agg1g2_kernel(
    const unsigned short* __restrict__ hs, const unsigned int* __restrict__ csr,
    const int4* __restrict__ nod, const float* __restrict__ bias /*b1*/,
    const unsigned short* __restrict__ Wt2, unsigned short* __restrict__ hs2, int N)
{
    __shared__ unsigned short As[64 * 128];   // a1 tile [row][k] bf16, swizzled
    __shared__ unsigned short Bs[64 * 128];   // Wt2 [col][k] bf16, swizzled
    __shared__ float dl[64];

    const int t = threadIdx.x;
    const int w = t >> 6, l = t & 63;
    const int n0 = blockIdx.x * 64;
    const int sub = l >> 4, q = l & 15;
    const int rowl = w * 4 + sub;             // 0..63: As row this lane fills
    const int n = n0 + rowl;

    // stage Wt2: 64x128 bf16 = 1024 uint4, one per thread
    {
        int r = t >> 4;                      // col (16 uint4 per 128-elem row)
        int cb = (t & 15) * 16;
        uint4 p = ((const uint4*)Wt2)[t];
        *(uint4*)((char*)Bs + r * 256 + (cb ^ ((r & 7) << 4))) = p;
    }

    float acc[8] = {};
    float dv = 0.f;
    if (n < N) {
        int4 se = nod[n];
        dv = __int_as_float(se.z);
        add8(acc, *(const uint4*)&hs[(size_t)n * 128 + q * 8]);   // self loop
        int j = se.x;
        const int e = se.y;
        for (; j + 1 < e; j += 2) {
            int c0 = csr[j], c1 = csr[j + 1];
            uint4 p0 = *(const uint4*)&hs[(size_t)c0 * 128 + q * 8];
            uint4 p1 = *(const uint4*)&hs[(size_t)c1 * 128 + q * 8];
            add8(acc, p0);
            add8(acc, p1);
        }
        if (j < e)
            add8(acc, *(const uint4*)&hs[(size_t)csr[j] * 128 + q * 8]);
    }

    // a1 row -> LDS (finite even for n>=N: acc=0, dv=0 -> relu(b1))
    {
        float4 b0 = ((const float4*)bias)[q * 2];
        float4 b1v = ((const float4*)bias)[q * 2 + 1];
        float v0 = fmaxf(dv * acc[0] + b0.x, 0.f), v1 = fmaxf(dv * acc[1] + b0.y, 0.f);
        float v2 = fmaxf(dv * acc[2] + b0.z, 0.f), v3 = fmaxf(dv * acc[3] + b0.w, 0.f);
        float v4 = fmaxf(dv * acc[4] + b1v.x, 0.f), v5 = fmaxf(dv * acc[5] + b1v.y, 0.f);
        float v6 = fmaxf(dv * acc[6] + b1v.z, 0.f), v7 = fmaxf(dv * acc[7] + b1v.w, 0.f);
        uint4 o;
        o.x = pack2bf(v0, v1); o.y = pack2bf(v2, v3);
        o.z = pack2bf(v4, v5); o.w = pack2bf(v6, v7);
        int cb = q * 16;
        *(uint4*)((char*)As + rowl * 256 + (cb ^ ((rowl & 7) << 4))) = o;
        if (q == 0) dl[rowl] = dv;
    }
    __syncthreads();

    // MFMA phase: wave w -> tile (mt = w>>2, ct = w&3); K = 128 (4 steps)
    const int lr = l & 15, lk = l >> 4;
    const int mt = w >> 2, ct = w & 3;

    bf16x8 af[4], bfr[4];
    #pragma unroll
    for (int kt = 0; kt < 4; ++kt) {
        int r = mt * 16 + lr;
        int cb = kt * 64 + lk * 16;
        af[kt] = *(const bf16x8*)((const char*)As + r * 256 + (cb ^ ((r & 7) << 4)));
        int c = ct * 16 + lr;
        bfr[kt] = *(const bf16x8*)((const char*)Bs + c * 256 + (cb ^ ((c & 7) << 4)));
    }
    f32x4 a = f32x4{0.f, 0.f, 0.f, 0.f};
    #pragma unroll
    for (int kt = 0; kt < 4; ++kt)
        a = __builtin_amdgcn_mfma_f32_16x16x32_bf16(af[kt], bfr[kt], a, 0, 0, 0);

    #pragma unroll
    for (int r = 0; r < 4; ++r) {
        int rowm = mt * 16 + lk * 4 + r;
        int grow = n0 + rowm;
        if (grow < N) {
            int c = ct * 16 + lr;
            float v = a[r] * dl[rowm];
            hs2[(size_t)grow * 64 + c] = (unsigned short)f2bf_rne(v);
        }
    }
}

// ------------------------------- AGG2 --------------------------------------
// C=64 bf16 rows (128B). 4 nodes per 256-thread block, one wave per node.
// Lane q=l&7 owns channels 8q..8q+7; group g=l>>3 strides by 8.
__global__ __launch_bounds__(256) void agg2_kernel(
    const unsigned short* __restrict__ hs, const unsigned int* __restrict__ csr,
    const int4* __restrict__ nod, const float* __restrict__ bias,
    float* __restrict__ out, int N)
{
    const int w = threadIdx.x >> 6, l = threadIdx.x & 63;
    const int n = blockIdx.x * 4 + w;
    if (n >= N) return;
    const int q = l & 7, g = l >> 3;

    int4 se = nod[n];
    float acc[8] = {};
    if (g == 0)                                        // self loop
        add8(acc, *(const uint4*)&hs[(size_t)n * 64 + q * 8]);

    int j = se.x + g;
    const int e = se.y;
    for (; j + 8 < e; j += 16) {
        int c0 = csr[j], c1 = csr[j + 8];
        uint4 p0 = *(const uint4*)&hs[(size_t)c0 * 64 + q * 8];
        uint4 p1 = *(const uint4*)&hs[(size_t)c1 * 64 + q * 8];
        add8(acc, p0);
        add8(acc, p1);
    }
    if (j < e)
        add8(acc, *(const uint4*)&hs[(size_t)csr[j] * 64 + q * 8]);

    #pragma unroll
    for (int i = 0; i < 8; ++i) {
        acc[i] += __shfl_xor(acc[i], 8);
        acc[i] += __shfl_xor(acc[i], 16);
        acc[i] += __shfl_xor(acc[i], 32);
    }

    if (g == 0) {
        float d = __int_as_float(se.z);
        float4 b0 = ((const float4*)bias)[q * 2];
        float4 b1 = ((const float4*)bias)[q * 2 + 1];
        float4 o0, o1;
        o0.x = d * acc[0] + b0.x; o0.y = d * acc[1] + b0.y;
        o0.z = d * acc[2] + b0.z; o0.w = d * acc[3] + b0.w;
        o1.x = d * acc[4] + b1.x; o1.y = d * acc[5] + b1.y;
        o1.z = d * acc[6] + b1.z; o1.w = d * acc[7] + b1.w;
        *(float4*)&out[(size_t)n * 64 + q * 8] = o0;
        *(float4*)&out[(size_t)n * 64 + q * 8 + 4] = o1;
    }
}

extern "C" void kernel_launch(void* const* d_in, const int* in_sizes, int n_in,
                              void* d_out, int out_size, void* d_ws, size_t ws_size,
                              hipStream_t stream)
{
    const float* x  = (const float*)d_in[0];
    const int*   ei = (const int*)d_in[1];
    const float* W1 = (const float*)d_in[2];
    const float* b1 = (const float*)d_in[3];
    const float* W2 = (const float*)d_in[4];
    const float* b2 = (const float*)d_in[5];
    float* out = (float*)d_out;

    const int N = in_sizes[0] / 128;          // 50000
    const int E = in_sizes[1] / 2;            // 800000
    const int* row = ei;                       // targets
    const int* col = ei + E;                   // sources
    const int NB = (N + 255) / 256;            // 196 buckets
    const int CE = (E + CHUNKS - 1) / CHUNKS;  // 3125 edges per chunk

    // workspace layout (256B aligned)
    char* ws = (char*)d_ws;
    size_t o = 0;
    auto take = [&](size_t bytes) { void* p = ws + o; o = (o + bytes + 255) & ~(size_t)255; return p; };
    int*   pos    = (int*)  take((size_t)(NB + 1) * CHUNKS * 4);
    unsigned int* bucketc = (unsigned int*)take((size_t)E * 4);        // chunk-private regions
    unsigned int* csrf    = (unsigned int*)take((size_t)NB * CAP * 4); // final CSR, base b*CAP
    float* dinv   = (float*)take((size_t)N * 4);
    int4*  nod    = (int4*) take((size_t)N * 16);
    unsigned short* Wt1 = (unsigned short*)take(128 * 128 * 2);
    unsigned short* Wt2 = (unsigned short*)take(64 * 128 * 2);
    unsigned short* hs  = (unsigned short*)take((size_t)N * 128 * 2);  // layer-1 transformed
    unsigned short* hs2 = (unsigned short*)take((size_t)N * 64 * 2);   // layer-2 transformed

    p1_kernel<<<CHUNKS, 256, 0, stream>>>(row, col, E, CE, NB, W1, W2, Wt1, Wt2,
                                          pos, bucketc);
    p2_kernel<<<NB, 256, 0, stream>>>(pos, bucketc, csrf, dinv, nod, N, CE);

    // layer 1: hs = bf16((X @ W1) * dinv)
    gemm_mfma_kernel<<<(N + 63) / 64, 256, 0, stream>>>(x, Wt1, dinv, hs, N);

    // fused: a1 = relu(dinv*(gather hs)+b1) [LDS] ; hs2 = bf16((a1 @ W2)*dinv)
    agg1g2_kernel<<<(N + 63) / 64, 1024, 0, stream>>>(hs, csrf, nod, b1, Wt2, hs2, N);

    // layer 2 aggregate: out = dinv*(gather hs2) + b2
    agg2_kernel<<<(N + 3) / 4, 256, 0, stream>>>(hs2, csrf, nod, b2, out, N);
}

// Round 11
// 101.551 us; speedup vs baseline: 2.3801x; 1.0140x over previous
//
#include <hip/hip_runtime.h>

// ---------------------------------------------------------------------------
// GCN 2-layer encoder for MI355X.
//   p1 (per-chunk LDS hist+scan+private-region scatter, + wtrans folded in)
//   p2 (per-bucket fragment gather -> LDS hist+scan -> fixed-base CSR, nod/dinv)
//   -> MFMA-GEMM1(f32 in ->bf16,*dinv) -> FUSED AGG1+GEMM2 (aggregate 64
//      nodes/block into LDS a1 tile, MFMA vs Wt2, write hs2) -> AGG2(+b2)
// out[r] = dinv[r] * (sum_{e: row=r} hs[col_e] + hs[r]) + b   with hs = (X@W)*dinv
// Lesson r7: grid.sync() costs ~35us/sync on 8 non-coherent XCDs -- never.
// Lesson r9: wave->row map must cover the WHOLE LDS tile.
// r11: gather MLP x2 (unroll x4 per 16-lane group) -- gathers are latency-
//   bound (205MB logical / 6us BW-floor vs ~45us observed at unroll x2).
// ---------------------------------------------------------------------------

#define CHUNKS 256             // edge chunks (p1 grid)
#define CAP    7168            // per-bucket CSR capacity (and LDS ent capacity)

typedef short bf16x8 __attribute__((ext_vector_type(8)));
typedef float f32x4 __attribute__((ext_vector_type(4)));

__device__ __forceinline__ float bf2f(unsigned int u16) {
    return __uint_as_float(u16 << 16);
}
__device__ __forceinline__ unsigned int f2bf_rne(float f) {
    unsigned int u = __float_as_uint(f);
    return (u + 0x7fffu + ((u >> 16) & 1u)) >> 16;
}
__device__ __forceinline__ unsigned int pack2bf(float a, float b) {
    return f2bf_rne(a) | (f2bf_rne(b) << 16);
}
__device__ __forceinline__ void add8(float* acc, uint4 p) {
    acc[0] += bf2f(p.x & 0xffffu); acc[1] += bf2f(p.x >> 16);
    acc[2] += bf2f(p.y & 0xffffu); acc[3] += bf2f(p.y >> 16);
    acc[4] += bf2f(p.z & 0xffffu); acc[5] += bf2f(p.z >> 16);
    acc[6] += bf2f(p.w & 0xffffu); acc[7] += bf2f(p.w >> 16);
}

// ------------------------------ build p1 -----------------------------------
__global__ __launch_bounds__(256) void p1_kernel(
    const int* __restrict__ row, const int* __restrict__ col, int E, int CE, int NB,
    const float* __restrict__ W1, const float* __restrict__ W2,
    unsigned short* __restrict__ Wt1, unsigned short* __restrict__ Wt2,
    int* __restrict__ pos, unsigned int* __restrict__ bucketc)
{
    __shared__ int hist[256], scn[256], cur[256];
    const int c = blockIdx.x, t = threadIdx.x;
    const int s = c * CE, e = min(E, s + CE);

    hist[t] = 0;
    __syncthreads();
    for (int i = s + t; i < e; i += 256) atomicAdd(&hist[row[i] >> 8], 1);
    {   // wtrans: 24576 elements over the grid
        int i = c * 256 + t;
        if (i < 128 * 128) {
            int k = i >> 7, cc = i & 127;
            Wt1[cc * 128 + k] = (unsigned short)f2bf_rne(W1[i]);
        } else if (i < 128 * 128 + 128 * 64) {
            int j = i - 128 * 128;
            int k = j >> 6, cc = j & 63;
            Wt2[cc * 128 + k] = (unsigned short)f2bf_rne(W2[j]);
        }
    }
    __syncthreads();

    int v = hist[t];
    scn[t] = v;
    __syncthreads();
    #pragma unroll
    for (int d = 1; d < 256; d <<= 1) {
        int xv = (t >= d) ? scn[t - d] : 0;
        __syncthreads();
        scn[t] += xv;
        __syncthreads();
    }
    int excl = scn[t] - v;
    if (t <= NB) pos[t * CHUNKS + c] = excl;   // row NB = chunk total
    cur[t] = excl;
    __syncthreads();

    for (int i = s + t; i < e; i += 256) {
        int r = row[i];
        int p = atomicAdd(&cur[r >> 8], 1);
        bucketc[s + p] = (unsigned)(r & 255) | ((unsigned)col[i] << 8);
    }
}

// ------------------------------ build p2 -----------------------------------
__global__ __launch_bounds__(256) void p2_kernel(
    const int* __restrict__ pos, const unsigned int* __restrict__ bucketc,
    unsigned int* __restrict__ csrf, float* __restrict__ dinv,
    int4* __restrict__ nod, int N, int CE)
{
    __shared__ unsigned int ent[CAP];      // 28KB
    __shared__ int stmp[256], hist[256], scn[256], cnt2[256], smtot[1];
    const int b = blockIdx.x, t = threadIdx.x;

    const int p0 = pos[b * CHUNKS + t];
    const int p1 = pos[(b + 1) * CHUNKS + t];
    const int cnt = p1 - p0;

    stmp[t] = cnt;
    hist[t] = 0;
    cnt2[t] = 0;
    __syncthreads();
    #pragma unroll
    for (int d = 1; d < 256; d <<= 1) {
        int xv = (t >= d) ? stmp[t - d] : 0;
        __syncthreads();
        stmp[t] += xv;
        __syncthreads();
    }
    const int fbase = stmp[t] - cnt;
    if (t == 255) smtot[0] = stmp[255];
    __syncthreads();
    const int m = min(smtot[0], CAP);

    {
        const int src = t * CE + p0;
        int i = 0;
        for (; i + 1 < cnt; i += 2) {
            unsigned int u0 = bucketc[src + i];
            unsigned int u1 = bucketc[src + i + 1];
            int d0 = fbase + i;
            if (d0 + 1 < CAP) {
                ent[d0] = u0; ent[d0 + 1] = u1;
                atomicAdd(&hist[u0 & 255u], 1);
                atomicAdd(&hist[u1 & 255u], 1);
            }
        }
        if (i < cnt) {
            unsigned int u0 = bucketc[src + i];
            int d0 = fbase + i;
            if (d0 < CAP) {
                ent[d0] = u0;
                atomicAdd(&hist[u0 & 255u], 1);
            }
        }
    }
    __syncthreads();

    int h = hist[t];
    scn[t] = h;
    __syncthreads();
    #pragma unroll
    for (int d = 1; d < 256; d <<= 1) {
        int xv = (t >= d) ? scn[t - d] : 0;
        __syncthreads();
        scn[t] += xv;
        __syncthreads();
    }
    int base = scn[t] - h;

    int node = b * 256 + t;
    if (node < N) {
        float dv = rsqrtf((float)(h + 1));   // +1 self loop
        dinv[node] = dv;
        nod[node] = make_int4(b * CAP + base, b * CAP + base + h, __float_as_int(dv), 0);
    }
    scn[t] = base;
    __syncthreads();

    for (int i = t; i < m; i += 256) {
        unsigned int v = ent[i];
        int r = v & 255u;
        int slot = atomicAdd(&cnt2[r], 1);
        csrf[b * CAP + scn[r] + slot] = v >> 8;   // col
    }
}

// ------------------------------- GEMM1 -------------------------------------
// out[m][c] = bf16( dinv[m] * sum_k bf16(X[m][k]) * Wt[c][k] ), COUT=128.
__global__ __launch_bounds__(256) void gemm_mfma_kernel(
    const float* __restrict__ X, const unsigned short* __restrict__ Wt,
    const float* __restrict__ dinv, unsigned short* __restrict__ out, int N)
{
    constexpr int COUT = 128;
    __shared__ unsigned short As[64 * 128];      // [row][k] bf16, swizzled
    __shared__ unsigned short Bs[COUT * 128];    // [col][k] bf16, swizzled
    __shared__ float dl[64];

    const int t = threadIdx.x;
    const int m0 = blockIdx.x * 64;

    #pragma unroll
    for (int i = 0; i < 8; ++i) {
        int f = i * 256 + t;          // float4 index into 64x128 f32 tile
        int r = f >> 5, c4 = f & 31;
        int rg = m0 + r;
        float4 v = (rg < N) ? ((const float4*)X)[(size_t)rg * 32 + c4]
                            : make_float4(0.f, 0.f, 0.f, 0.f);
        uint2 p;
        p.x = pack2bf(v.x, v.y);
        p.y = pack2bf(v.z, v.w);
        int cb = c4 * 8;
        *(uint2*)((char*)As + r * 256 + (cb ^ ((r & 7) << 4))) = p;
    }
    #pragma unroll
    for (int i = 0; i < 16; ++i) {
        int f = i * 256 + t;              // uint2 index into COUT x 128 bf16
        int r = f >> 5;
        int cb = (f & 31) * 8;
        uint2 p = ((const uint2*)Wt)[f];
        *(uint2*)((char*)Bs + r * 256 + (cb ^ ((r & 7) << 4))) = p;
    }
    if (t < 64) dl[t] = (m0 + t < N) ? dinv[m0 + t] : 0.f;
    __syncthreads();

    const int w = t >> 6, l = t & 63;
    const int lr = l & 15, lk = l >> 4;

    bf16x8 af[4][4];                       // [mt][kt]
    #pragma unroll
    for (int mt = 0; mt < 4; ++mt)
        #pragma unroll
        for (int kt = 0; kt < 4; ++kt) {
            int r = mt * 16 + lr;
            int cb = kt * 64 + lk * 16;
            af[mt][kt] = *(const bf16x8*)((const char*)As + r * 256 + (cb ^ ((r & 7) << 4)));
        }
    bf16x8 bfr[2][4];
    #pragma unroll
    for (int ct = 0; ct < 2; ++ct)
        #pragma unroll
        for (int kt = 0; kt < 4; ++kt) {
            int c = w * 32 + ct * 16 + lr;
            int cb = kt * 64 + lk * 16;
            bfr[ct][kt] = *(const bf16x8*)((const char*)Bs + c * 256 + (cb ^ ((c & 7) << 4)));
        }

    f32x4 acc[4][2];
    #pragma unroll
    for (int mt = 0; mt < 4; ++mt)
        #pragma unroll
        for (int ct = 0; ct < 2; ++ct)
            acc[mt][ct] = f32x4{0.f, 0.f, 0.f, 0.f};

    #pragma unroll
    for (int kt = 0; kt < 4; ++kt)
        #pragma unroll
        for (int mt = 0; mt < 4; ++mt)
            #pragma unroll
            for (int ct = 0; ct < 2; ++ct)
                acc[mt][ct] = __builtin_amdgcn_mfma_f32_16x16x32_bf16(
                    af[mt][kt], bfr[ct][kt], acc[mt][ct], 0, 0, 0);

    // epilogue: C/D layout col = lane&15, row = (lane>>4)*4 + reg
    #pragma unroll
    for (int mt = 0; mt < 4; ++mt) {
        #pragma unroll
        for (int ct = 0; ct < 2; ++ct) {
            #pragma unroll
            for (int r = 0; r < 4; ++r) {
                int rowl = mt * 16 + lk * 4 + r;
                int grow = m0 + rowl;
                if (grow < N) {
                    int c = w * 32 + ct * 16 + lr;
                    float v = acc[mt][ct][r] * dl[rowl];
                    out[(size_t)grow * COUT + c] = (unsigned short)f2bf_rne(v);
                }
            }
        }
    }
}

// --------------------- FUSED AGG1 + GEMM2 ----------------------------------
// Block = 64 nodes, 16 waves (1024 thr). Wave w owns 4 nodes: lane l ->
// (sub = l>>4, q = l&15); node n = n0 + w*4 + sub; lane q owns channels
// 8q..8q+7 EXCLUSIVELY (16B uint4 loads, no cross-lane reduce). Gather loop
// unrolled x4 (4 independent rows in flight per group). a1 row =
// relu(dv*acc + b1) -> LDS As (swizzled). One barrier, then 64x64x128 MFMA
// vs LDS Bs=Wt2 (wave w -> tile mt=w>>2, ct=w&3), epilogue *dinv, write hs2.
__global__ __launch_bounds__(1024) void agg1g2_kernel(
    const unsigned short* __restrict__ hs, const unsigned int* __restrict__ csr,
    const int4* __restrict__ nod, const float* __restrict__ bias /*b1*/,
    const unsigned short* __restrict__ Wt2, unsigned short* __restrict__ hs2, int N)
{
    __shared__ unsigned short As[64 * 128];   // a1 tile [row][k] bf16, swizzled
    __shared__ unsigned short Bs[64 * 128];   // Wt2 [col][k] bf16, swizzled
    __shared__ float dl[64];

    const int t = threadIdx.x;
    const int w = t >> 6, l = t & 63;
    const int n0 = blockIdx.x * 64;
    const int sub = l >> 4, q = l & 15;
    const int rowl = w * 4 + sub;             // 0..63: As row this lane fills
    const int n = n0 + rowl;

    // stage Wt2: 64x128 bf16 = 1024 uint4, one per thread
    {
        int r = t >> 4;                      // col (16 uint4 per 128-elem row)
        int cb = (t & 15) * 16;
        uint4 p = ((const uint4*)Wt2)[t];
        *(uint4*)((char*)Bs + r * 256 + (cb ^ ((r & 7) << 4))) = p;
    }

    float acc[8] = {};
    float dv = 0.f;
    if (n < N) {
        int4 se = nod[n];
        dv = __int_as_float(se.z);
        add8(acc, *(const uint4*)&hs[(size_t)n * 128 + q * 8]);   // self loop
        int j = se.x;
        const int e = se.y;
        for (; j + 3 < e; j += 4) {          // 4 rows in flight per group
            int c0 = csr[j], c1 = csr[j + 1], c2 = csr[j + 2], c3 = csr[j + 3];
            uint4 p0 = *(const uint4*)&hs[(size_t)c0 * 128 + q * 8];
            uint4 p1 = *(const uint4*)&hs[(size_t)c1 * 128 + q * 8];
            uint4 p2 = *(const uint4*)&hs[(size_t)c2 * 128 + q * 8];
            uint4 p3 = *(const uint4*)&hs[(size_t)c3 * 128 + q * 8];
            add8(acc, p0);
            add8(acc, p1);
            add8(acc, p2);
            add8(acc, p3);
        }
        for (; j < e; ++j)
            add8(acc, *(const uint4*)&hs[(size_t)csr[j] * 128 + q * 8]);
    }

    // a1 row -> LDS (finite even for n>=N: acc=0, dv=0 -> relu(b1))
    {
        float4 b0 = ((const float4*)bias)[q * 2];
        float4 b1v = ((const float4*)bias)[q * 2 + 1];
        float v0 = fmaxf(dv * acc[0] + b0.x, 0.f), v1 = fmaxf(dv * acc[1] + b0.y, 0.f);
        float v2 = fmaxf(dv * acc[2] + b0.z, 0.f), v3 = fmaxf(dv * acc[3] + b0.w, 0.f);
        float v4 = fmaxf(dv * acc[4] + b1v.x, 0.f), v5 = fmaxf(dv * acc[5] + b1v.y, 0.f);
        float v6 = fmaxf(dv * acc[6] + b1v.z, 0.f), v7 = fmaxf(dv * acc[7] + b1v.w, 0.f);
        uint4 o;
        o.x = pack2bf(v0, v1); o.y = pack2bf(v2, v3);
        o.z = pack2bf(v4, v5); o.w = pack2bf(v6, v7);
        int cb = q * 16;
        *(uint4*)((char*)As + rowl * 256 + (cb ^ ((rowl & 7) << 4))) = o;
        if (q == 0) dl[rowl] = dv;
    }
    __syncthreads();

    // MFMA phase: wave w -> tile (mt = w>>2, ct = w&3); K = 128 (4 steps)
    const int lr = l & 15, lk = l >> 4;
    const int mt = w >> 2, ct = w & 3;

    bf16x8 af[4], bfr[4];
    #pragma unroll
    for (int kt = 0; kt < 4; ++kt) {
        int r = mt * 16 + lr;
        int cb = kt * 64 + lk * 16;
        af[kt] = *(const bf16x8*)((const char*)As + r * 256 + (cb ^ ((r & 7) << 4)));
        int c = ct * 16 + lr;
        bfr[kt] = *(const bf16x8*)((const char*)Bs + c * 256 + (cb ^ ((c & 7) << 4)));
    }
    f32x4 a = f32x4{0.f, 0.f, 0.f, 0.f};
    #pragma unroll
    for (int kt = 0; kt < 4; ++kt)
        a = __builtin_amdgcn_mfma_f32_16x16x32_bf16(af[kt], bfr[kt], a, 0, 0, 0);

    #pragma unroll
    for (int r = 0; r < 4; ++r) {
        int rowm = mt * 16 + lk * 4 + r;
        int grow = n0 + rowm;
        if (grow < N) {
            int c = ct * 16 + lr;
            float v = a[r] * dl[rowm];
            hs2[(size_t)grow * 64 + c] = (unsigned short)f2bf_rne(v);
        }
    }
}

// ------------------------------- AGG2 --------------------------------------
// C=64 bf16 rows (128B). 4 nodes per 256-thread block, one wave per node.
// Lane q=l&7 owns channels 8q..8q+7; group g=l>>3 strides by 8 (16 rows in
// flight per wave via unroll x2).
__global__ __launch_bounds__(256) void agg2_kernel(
    const unsigned short* __restrict__ hs, const unsigned int* __restrict__ csr,
    const int4* __restrict__ nod, const float* __restrict__ bias,
    float* __restrict__ out, int N)
{
    const int w = threadIdx.x >> 6, l = threadIdx.x & 63;
    const int n = blockIdx.x * 4 + w;
    if (n >= N) return;
    const int q = l & 7, g = l >> 3;

    int4 se = nod[n];
    float acc[8] = {};
    if (g == 0)                                        // self loop
        add8(acc, *(const uint4*)&hs[(size_t)n * 64 + q * 8]);

    int j = se.x + g;
    const int e = se.y;
    for (; j + 8 < e; j += 16) {
        int c0 = csr[j], c1 = csr[j + 8];
        uint4 p0 = *(const uint4*)&hs[(size_t)c0 * 64 + q * 8];
        uint4 p1 = *(const uint4*)&hs[(size_t)c1 * 64 + q * 8];
        add8(acc, p0);
        add8(acc, p1);
    }
    if (j < e)
        add8(acc, *(const uint4*)&hs[(size_t)csr[j] * 64 + q * 8]);

    #pragma unroll
    for (int i = 0; i < 8; ++i) {
        acc[i] += __shfl_xor(acc[i], 8);
        acc[i] += __shfl_xor(acc[i], 16);
        acc[i] += __shfl_xor(acc[i], 32);
    }

    if (g == 0) {
        float d = __int_as_float(se.z);
        float4 b0 = ((const float4*)bias)[q * 2];
        float4 b1 = ((const float4*)bias)[q * 2 + 1];
        float4 o0, o1;
        o0.x = d * acc[0] + b0.x; o0.y = d * acc[1] + b0.y;
        o0.z = d * acc[2] + b0.z; o0.w = d * acc[3] + b0.w;
        o1.x = d * acc[4] + b1.x; o1.y = d * acc[5] + b1.y;
        o1.z = d * acc[6] + b1.z; o1.w = d * acc[7] + b1.w;
        *(float4*)&out[(size_t)n * 64 + q * 8] = o0;
        *(float4*)&out[(size_t)n * 64 + q * 8 + 4] = o1;
    }
}

extern "C" void kernel_launch(void* const* d_in, const int* in_sizes, int n_in,
                              void* d_out, int out_size, void* d_ws, size_t ws_size,
                              hipStream_t stream)
{
    const float* x  = (const float*)d_in[0];
    const int*   ei = (const int*)d_in[1];
    const float* W1 = (const float*)d_in[2];
    const float* b1 = (const float*)d_in[3];
    const float* W2 = (const float*)d_in[4];
    const float* b2 = (const float*)d_in[5];
    float* out = (float*)d_out;

    const int N = in_sizes[0] / 128;          // 50000
    const int E = in_sizes[1] / 2;            // 800000
    const int* row = ei;                       // targets
    const int* col = ei + E;                   // sources
    const int NB = (N + 255) / 256;            // 196 buckets
    const int CE = (E + CHUNKS - 1) / CHUNKS;  // 3125 edges per chunk

    // workspace layout (256B aligned)
    char* ws = (char*)d_ws;
    size_t o = 0;
    auto take = [&](size_t bytes) { void* p = ws + o; o = (o + bytes + 255) & ~(size_t)255; return p; };
    int*   pos    = (int*)  take((size_t)(NB + 1) * CHUNKS * 4);
    unsigned int* bucketc = (unsigned int*)take((size_t)E * 4);        // chunk-private regions
    unsigned int* csrf    = (unsigned int*)take((size_t)NB * CAP * 4); // final CSR, base b*CAP
    float* dinv   = (float*)take((size_t)N * 4);
    int4*  nod    = (int4*) take((size_t)N * 16);
    unsigned short* Wt1 = (unsigned short*)take(128 * 128 * 2);
    unsigned short* Wt2 = (unsigned short*)take(64 * 128 * 2);
    unsigned short* hs  = (unsigned short*)take((size_t)N * 128 * 2);  // layer-1 transformed
    unsigned short* hs2 = (unsigned short*)take((size_t)N * 64 * 2);   // layer-2 transformed

    p1_kernel<<<CHUNKS, 256, 0, stream>>>(row, col, E, CE, NB, W1, W2, Wt1, Wt2,
                                          pos, bucketc);
    p2_kernel<<<NB, 256, 0, stream>>>(pos, bucketc, csrf, dinv, nod, N, CE);

    // layer 1: hs = bf16((X @ W1) * dinv)
    gemm_mfma_kernel<<<(N + 63) / 64, 256, 0, stream>>>(x, Wt1, dinv, hs, N);

    // fused: a1 = relu(dinv*(gather hs)+b1) [LDS] ; hs2 = bf16((a1 @ W2)*dinv)
    agg1g2_kernel<<<(N + 63) / 64, 1024, 0, stream>>>(hs, csrf, nod, b1, Wt2, hs2, N);

    // layer 2 aggregate: out = dinv*(gather hs2) + b2
    agg2_kernel<<<(N + 3) / 4, 256, 0, stream>>>(hs2, csrf, nod, b2, out, N);
}